// Round 17
// baseline (197.114 us; speedup 1.0000x reference)
//
#include <hip/hip_runtime.h>
#include <hip/hip_bf16.h>
#include <math.h>

#define D_MODEL 1024
#define D_INNER 2048
#define D_STATE 128
#define NHEADS 32
#define HEADDIM 64
#define CHUNK 64
#define B_SZ 2
#define LSEQ 2048
#define BL (B_SZ*LSEQ)                              // 4096
#define DPROJ (2*D_INNER + 2*D_STATE + NHEADS)      // 4384
#define CONV_DIM (D_INNER + 2*D_STATE)              // 2304
#define NCHUNK (LSEQ/CHUNK)                         // 32
#define NPAD1 4480                                  // DPROJ padded to x128
#define EPSF 1e-5f

typedef __attribute__((ext_vector_type(8))) _Float16 half8;
typedef __attribute__((ext_vector_type(4))) _Float16 half4;
typedef __attribute__((ext_vector_type(4))) float f32x4;

__device__ __forceinline__ float siluf(float v){ return v / (1.0f + expf(-v)); }
__device__ __forceinline__ float softplusf(float v){ return v > 20.0f ? v : log1pf(expf(v)); }
__device__ __forceinline__ unsigned short f2h(float x){
  union { _Float16 h; unsigned short u; } v; v.h = (_Float16)x;
  return v.u;
}
__device__ __forceinline__ float h2f(unsigned short x){
  union { unsigned short u; _Float16 h; } v; v.u = x;
  return (float)v.h;
}
__device__ __forceinline__ _Float16 h2h(unsigned short x){
  union { unsigned short u; _Float16 h; } v; v.u = x;
  return v.h;
}

typedef const __attribute__((address_space(1))) void gvoid_t;
typedef __attribute__((address_space(3))) void lvoid_t;
__device__ __forceinline__ void gl_lds16(const void* gsrc, void* ldst) {
  gvoid_t* g = reinterpret_cast<gvoid_t*>((uintptr_t)gsrc);
  lvoid_t* l = reinterpret_cast<lvoid_t*>((unsigned int)(uintptr_t)ldst);
  __builtin_amdgcn_global_load_lds(g, l, 16, 0, 0);
}

#define NU4  (BL*D_MODEL/4)
#define NW4  (NPAD1*D_MODEL/4)
#define NWo4 (D_MODEL*D_INNER/4)
#define NCVT (NU4+NW4+NWo4)

// ---------- fused converters ----------
__global__ void cvt_all(const float* __restrict__ u, const float* __restrict__ W_in,
                        const float* __restrict__ W_out, const float* __restrict__ norm_w,
                        unsigned short* __restrict__ u_h, unsigned short* __restrict__ Win_h,
                        unsigned short* __restrict__ Wg_h) {
  int i = blockIdx.x*256 + threadIdx.x;
  if (i >= NCVT) return;
  if (i < NU4) {
    float4 v = *(const float4*)(u + (size_t)i*4);
    ushort4 o; o.x=f2h(v.x); o.y=f2h(v.y); o.z=f2h(v.z); o.w=f2h(v.w);
    *(ushort4*)(u_h + (size_t)i*4) = o;
  } else if (i < NU4 + NW4) {
    int q = i - NU4;
    int row = q / (D_MODEL/4);
    ushort4 o; o.x=0; o.y=0; o.z=0; o.w=0;
    if (row < DPROJ) {
      float4 v = *(const float4*)(W_in + (size_t)q*4);
      o.x=f2h(v.x); o.y=f2h(v.y); o.z=f2h(v.z); o.w=f2h(v.w);
    }
    *(ushort4*)(Win_h + (size_t)q*4) = o;
  } else {
    int q = i - NU4 - NW4;
    int colq = q % (D_INNER/4);
    float4 v = *(const float4*)(W_out + (size_t)q*4);
    float4 g = *(const float4*)(norm_w + (size_t)colq*4);
    ushort4 o; o.x=f2h(v.x*g.x); o.y=f2h(v.y*g.y); o.z=f2h(v.z*g.z); o.w=f2h(v.w*g.w);
    *(ushort4*)(Wg_h + (size_t)q*4) = o;
  }
}

// ---------- GEMM1: 128x128, 4 slots, 2 K-tiles per barrier pair, region-mapped ----------
template<int OUT_F16>
__global__ __launch_bounds__(256) void gemm_f16_pipe(const unsigned short* __restrict__ A,
    const unsigned short* __restrict__ W, void* __restrict__ Cv,
    const float* __restrict__ Sc, int N, int K) {
  __shared__ unsigned short lds[4*2*4096];          // 64 KB -> 2 blocks/CU
  const int t   = threadIdx.x;
  const int wid = t >> 6, l = t & 63;
  const int gx = gridDim.x, gy = gridDim.y;         // gy % 8 == 0
  int bid = blockIdx.y * gx + blockIdx.x;
  int k   = bid & 7;
  int j   = bid >> 3;
  int rpx = gy >> 3;
  int r   = j % rpx;
  int colIdx = j / rpx;
  int row = k*rpx + r;
  int col = (colIdx + k*(gx >> 3)) % gx;
  const int m0 = row * 128;
  const int n0 = col * 128;
  const int wr = wid >> 1, wc = wid & 1;
  const int fr = l & 15, cg = l >> 4;
  const int NT = K >> 5;

  int srow[2]; int scol[2];
  #pragma unroll
  for (int i=0;i<2;++i){
    int s = i*256 + t;
    int rr = s >> 2, c = s & 3;
    int sw = (rr + (rr>>2)) & 3;
    srow[i] = rr; scol[i] = (c ^ sw) * 8;
  }
  const unsigned short* Abase = A + (size_t)m0 * K;
  const unsigned short* Wbase = W + (size_t)n0 * K;

#define STAGE(tt, slot) { \
    int kk = (tt) << 5; \
    unsigned short* La = &lds[(slot)*8192]; \
    unsigned short* Lb = &lds[(slot)*8192 + 4096]; \
    gl_lds16(Abase + (size_t)srow[0]*K + kk + scol[0], (char*)La + (0*256+t)*16); \
    gl_lds16(Abase + (size_t)srow[1]*K + kk + scol[1], (char*)La + (1*256+t)*16); \
    gl_lds16(Wbase + (size_t)srow[0]*K + kk + scol[0], (char*)Lb + (0*256+t)*16); \
    gl_lds16(Wbase + (size_t)srow[1]*K + kk + scol[1], (char*)Lb + (1*256+t)*16); \
  }

#define COMPUTE(slot) { \
    const unsigned short* La = &lds[(slot)*8192]; \
    const unsigned short* Lb = &lds[(slot)*8192 + 4096]; \
    half8 af[4], bfv[4]; \
    _Pragma("unroll") \
    for (int m=0;m<4;++m){ \
      int rr = wr*64 + m*16 + fr; \
      int sw = (rr + (rr>>2)) & 3; \
      af[m] = *(const half8*)&La[(rr*4 + (cg ^ sw))*8]; \
    } \
    _Pragma("unroll") \
    for (int n=0;n<4;++n){ \
      int rr = wc*64 + n*16 + fr; \
      int sw = (rr + (rr>>2)) & 3; \
      bfv[n] = *(const half8*)&Lb[(rr*4 + (cg ^ sw))*8]; \
    } \
    __builtin_amdgcn_s_setprio(1); \
    _Pragma("unroll") \
    for (int m=0;m<4;++m) \
      _Pragma("unroll") \
      for (int n=0;n<4;++n) \
        acc[m][n] = __builtin_amdgcn_mfma_f32_16x16x32_f16(af[m], bfv[n], acc[m][n], 0, 0, 0); \
    __builtin_amdgcn_s_setprio(0); \
  }

  f32x4 acc[4][4] = {};
  STAGE(0, 0);
  STAGE(1, 1);
  STAGE(2, 2);
  STAGE(3, 3);

  for (int tt = 0; tt < NT; tt += 2) {
    if (tt + 4 < NT) { asm volatile("s_waitcnt vmcnt(8)" ::: "memory"); }
    else             { asm volatile("s_waitcnt vmcnt(0)" ::: "memory"); }
    __builtin_amdgcn_s_barrier();
    asm volatile("" ::: "memory");

    COMPUTE(tt & 3);
    COMPUTE((tt + 1) & 3);

    asm volatile("s_waitcnt lgkmcnt(0)" ::: "memory");
    __builtin_amdgcn_s_barrier();
    asm volatile("" ::: "memory");
    if (tt + 4 < NT) {
      STAGE(tt + 4, (tt + 4) & 3);
      if (tt + 5 < NT) STAGE(tt + 5, (tt + 5) & 3);
    }
  }
#undef COMPUTE
#undef STAGE

  const int crow = m0 + wr*64 + (l >> 4) * 4;
  const int ccol0 = n0 + wc*64 + fr;
  #pragma unroll
  for (int m = 0; m < 4; ++m) {
    #pragma unroll
    for (int n = 0; n < 4; ++n) {
      int colo = ccol0 + n*16;
      if (colo < N) {
        if (OUT_F16) {
          unsigned short* cp = (unsigned short*)Cv + (size_t)(crow + m*16)*N + colo;
          #pragma unroll
          for (int jj = 0; jj < 4; ++jj) cp[(size_t)jj*N] = f2h(acc[m][n][jj]);
        } else {
          float* cp = (float*)Cv + (size_t)(crow + m*16)*N + colo;
          #pragma unroll
          for (int jj = 0; jj < 4; ++jj) cp[(size_t)jj*N] = acc[m][n][jj] * Sc[crow + m*16 + jj];
        }
      }
    }
  }
}

// ---------- GEMM2: 64x128 tile, 4 waves, 48 KB LDS, inline RMS from raw sums ----------
__global__ __launch_bounds__(256) void gemm_f16_64(const unsigned short* __restrict__ A,
    const unsigned short* __restrict__ W, float* __restrict__ C,
    const float* __restrict__ ScRaw, int N, int K) {
  __shared__ unsigned short lds[4*6144];            // 4 slots x 12KB = 48KB
  const int t   = threadIdx.x;
  const int wid = t >> 6, l = t & 63;
  const int gx = gridDim.x, gy = gridDim.y;         // 8 x 64
  int bid = blockIdx.y * gx + blockIdx.x;
  int k   = bid & 7;
  int j   = bid >> 3;
  int rpx = gy >> 3;                                // 8
  int r   = j % rpx;
  int colIdx = j / rpx;
  const int m0 = (k*rpx + r) * 64;
  const int n0 = ((colIdx + k*(gx >> 3)) % gx) * 128;
  const int fr = l & 15, cg = l >> 4;
  const int NT = K >> 5;                            // 64 (even)

  const int srw  = t >> 2;
  const int sw_  = (srw + (srw>>2)) & 3;
  const int scl  = ((t & 3) ^ sw_) * 8;
  const unsigned short* Abase = A + (size_t)m0 * K;
  const unsigned short* Wbase = W + (size_t)n0 * K;

#define STG64(tt, slot) { \
    int kk = (tt) << 5; \
    char* Ls = (char*)lds + (slot)*12288; \
    gl_lds16(Abase + (size_t)srw*K + kk + scl,        Ls + t*16); \
    gl_lds16(Wbase + (size_t)srw*K + kk + scl,        Ls + 4096 + t*16); \
    gl_lds16(Wbase + (size_t)(64+srw)*K + kk + scl,   Ls + 4096 + (256+t)*16); \
  }

#define CMP64(slot) { \
    const unsigned short* La = &lds[(slot)*6144]; \
    const unsigned short* Lb = &lds[(slot)*6144 + 2048]; \
    half8 af[4], bfv[2]; \
    _Pragma("unroll") \
    for (int m=0;m<4;++m){ \
      int rr = m*16 + fr; \
      int sw = (rr + (rr>>2)) & 3; \
      af[m] = *(const half8*)&La[(rr*4 + (cg ^ sw))*8]; \
    } \
    _Pragma("unroll") \
    for (int n=0;n<2;++n){ \
      int rr = wid*32 + n*16 + fr; \
      int sw = (rr + (rr>>2)) & 3; \
      bfv[n] = *(const half8*)&Lb[(rr*4 + (cg ^ sw))*8]; \
    } \
    __builtin_amdgcn_s_setprio(1); \
    _Pragma("unroll") \
    for (int m=0;m<4;++m) \
      _Pragma("unroll") \
      for (int n=0;n<2;++n) \
        acc[m][n] = __builtin_amdgcn_mfma_f32_16x16x32_f16(af[m], bfv[n], acc[m][n], 0, 0, 0); \
    __builtin_amdgcn_s_setprio(0); \
  }

  f32x4 acc[4][2] = {};
  STG64(0, 0);
  STG64(1, 1);
  STG64(2, 2);
  STG64(3, 3);

  for (int tt = 0; tt < NT; tt += 2) {
    if (tt + 4 < NT) { asm volatile("s_waitcnt vmcnt(6)" ::: "memory"); }
    else             { asm volatile("s_waitcnt vmcnt(0)" ::: "memory"); }
    __builtin_amdgcn_s_barrier();
    asm volatile("" ::: "memory");

    CMP64(tt & 3);
    CMP64((tt + 1) & 3);

    asm volatile("s_waitcnt lgkmcnt(0)" ::: "memory");
    __builtin_amdgcn_s_barrier();
    asm volatile("" ::: "memory");
    if (tt + 4 < NT) {
      STG64(tt + 4, (tt + 4) & 3);
      if (tt + 5 < NT) STG64(tt + 5, (tt + 5) & 3);
    }
  }
#undef CMP64
#undef STG64

  const int crow = m0 + cg * 4;
  const int ccol0 = n0 + wid*32 + fr;
  #pragma unroll
  for (int m = 0; m < 4; ++m) {
    #pragma unroll
    for (int n = 0; n < 2; ++n) {
      int colo = ccol0 + n*16;
      float* cp = C + (size_t)(crow + m*16)*N + colo;
      #pragma unroll
      for (int jj = 0; jj < 4; ++jj) {
        float scv = rsqrtf(ScRaw[crow + m*16 + jj] * (1.0f/D_INNER) + EPSF);
        cp[(size_t)jj*N] = acc[m][n][jj] * scv;
      }
    }
  }
}

// ---------- fused dt + per-chunk cumsum (+ zero sc_raw for y_mfma atomics) ----------
__global__ __launch_bounds__(64) void dtacum_kernel(const unsigned short* __restrict__ zx,
    const float* __restrict__ dt_bias, const float* __restrict__ A_log,
    float* __restrict__ dt, float* __restrict__ A_cum, float* __restrict__ sc_raw) {
  int blk = blockIdx.x;                             // (b*32+h)*32+c
  if (blk < 64) sc_raw[blk*64 + threadIdx.x] = 0.f; // zero 4096 floats (before y_mfma)
  int c = blk & 31, h = (blk >> 5) & 31, b = blk >> 10;
  int l = threadIdx.x;
  int row = b*LSEQ + c*CHUNK + l;
  float v = h2f(zx[(size_t)row*DPROJ + (2*D_INNER + 2*D_STATE) + h]) + dt_bias[h];
  float dtv = softplusf(v);
  dt[row*NHEADS + h] = dtv;
  float val = -expf(A_log[h]) * dtv;
  #pragma unroll
  for (int off = 1; off < 64; off <<= 1) {
    float nv = __shfl_up(val, off, 64);
    if (l >= off) val += nv;
  }
  A_cum[blk*64 + l] = val;
}

// causal depthwise conv (K=4) + bias + silu; fp16 in/out; 16 rows x 4 channels/thread
__global__ __launch_bounds__(256) void conv16_kernel(const unsigned short* __restrict__ zx,
    const float* __restrict__ w, const float* __restrict__ bias, unsigned short* __restrict__ xBC) {
  int idx = blockIdx.x*256 + threadIdx.x;           // over (BL/16) * (CONV_DIM/4)
  if (idx >= (BL/16)*(CONV_DIM/4)) return;
  int c4  = idx % (CONV_DIM/4);
  int rb  = idx / (CONV_DIM/4);
  int ch  = c4 * 4;
  int row0 = rb * 16;
  int l0   = row0 & (LSEQ-1);
  float4 r[19];
  #pragma unroll
  for (int jj=0;jj<19;++jj){
    int li = l0 + jj - 3;
    if (li >= 0) {
      ushort4 v = *(const ushort4*)&zx[(size_t)(row0 + jj - 3)*DPROJ + D_INNER + ch];
      r[jj] = make_float4(h2f(v.x), h2f(v.y), h2f(v.z), h2f(v.w));
    } else r[jj] = make_float4(0.f,0.f,0.f,0.f);
  }
  float4 wv[4];
  #pragma unroll
  for (int c=0;c<4;++c) wv[c] = *(const float4*)&w[(ch+c)*4];
  float4 bv = *(const float4*)&bias[ch];
  #pragma unroll
  for (int j=0;j<16;++j){
    float4 acc = bv;
    acc.x += wv[0].x*r[j].x + wv[0].y*r[j+1].x + wv[0].z*r[j+2].x + wv[0].w*r[j+3].x;
    acc.y += wv[1].x*r[j].y + wv[1].y*r[j+1].y + wv[1].z*r[j+2].y + wv[1].w*r[j+3].y;
    acc.z += wv[2].x*r[j].z + wv[2].y*r[j+1].z + wv[2].z*r[j+2].z + wv[2].w*r[j+3].z;
    acc.w += wv[3].x*r[j].w + wv[3].y*r[j+1].w + wv[3].z*r[j+2].w + wv[3].w*r[j+3].w;
    ushort4 o; o.x=f2h(siluf(acc.x)); o.y=f2h(siluf(acc.y)); o.z=f2h(siluf(acc.z)); o.w=f2h(siluf(acc.w));
    *(ushort4*)&xBC[(size_t)(row0+j)*CONV_DIM + ch] = o;
  }
}

// G[b,c][l][s] = sum_n C[l,n] * B[s,n]; 4 blocks per (b,c); fp16 G out
__global__ __launch_bounds__(256) void g_kernel(const unsigned short* __restrict__ xBC,
                                                unsigned short* __restrict__ G) {
  int blk = blockIdx.x >> 2;                        // b*32 + c
  int lq  = blockIdx.x & 3;
  int b = blk >> 5, c = blk & 31;
  __shared__ float Bsh[64][129];
  int t = threadIdx.x;
  int row0 = b*LSEQ + c*CHUNK;
  #pragma unroll
  for (int j=0;j<8;++j){
    int e0 = (j*256 + t)*4;                         // 0..8191
    int s = e0 >> 7, n = e0 & 127;
    ushort4 v = *(const ushort4*)&xBC[(size_t)(row0+s)*CONV_DIM + D_INNER + n];
    Bsh[s][n+0] = h2f(v.x); Bsh[s][n+1] = h2f(v.y);
    Bsh[s][n+2] = h2f(v.z); Bsh[s][n+3] = h2f(v.w);
  }
  __syncthreads();
  int l = lq*16 + (t >> 4), s0 = (t & 15) * 4;
  const unsigned short* Cp = &xBC[(size_t)(row0+l)*CONV_DIM + D_INNER + D_STATE];
  float acc[4] = {};
  #pragma unroll 4
  for (int n4=0;n4<32;++n4){
    ushort4 cv4 = *(const ushort4*)&Cp[n4*4];
    float cv[4] = { h2f(cv4.x), h2f(cv4.y), h2f(cv4.z), h2f(cv4.w) };
    #pragma unroll
    for (int kk=0;kk<4;++kk){
      #pragma unroll
      for (int j=0;j<4;++j) acc[j] += cv[kk] * Bsh[s0+j][n4*4+kk];
    }
  }
  unsigned short* Gp = &G[(size_t)blk*4096 + l*64 + s0];
  ushort4 o; o.x=f2h(acc[0]); o.y=f2h(acc[1]); o.z=f2h(acc[2]); o.w=f2h(acc[3]);
  *(ushort4*)Gp = o;
}

// ---------- MFMA states (fp16 out, vectorized staging) ----------
__global__ __launch_bounds__(256) void states_mfma(const unsigned short* __restrict__ xBC,
    const float* __restrict__ dt, const float* __restrict__ A_cum, unsigned short* __restrict__ states) {
  int blk = blockIdx.x;                             // (b*32+c)*32+h
  int h = blk & 31, c = (blk>>5)&31, b = blk>>10;
  __shared__ _Float16 Bt[128][72];                  // [n][s]
  __shared__ _Float16 xdT[64][72];                  // [p][s]
  __shared__ float Ac[64], dtl[64];
  int t = threadIdx.x;
  int wid = t >> 6, ln = t & 63;
  int row0 = b*LSEQ + c*CHUNK;
  if (t < 64){ Ac[t] = A_cum[((b*32+h)*32 + c)*64 + t]; dtl[t] = dt[(row0+t)*NHEADS + h]; }
  __syncthreads();
  float AcL = Ac[63];
  #pragma unroll
  for (int j=0;j<8;++j){
    int e0 = (j*256+t)*4;                           // 0..8191
    int s = e0 >> 7, n = e0 & 127;
    ushort4 v = *(const ushort4*)&xBC[(size_t)(row0+s)*CONV_DIM + D_INNER + n];
    Bt[n+0][s] = h2h(v.x); Bt[n+1][s] = h2h(v.y);
    Bt[n+2][s] = h2h(v.z); Bt[n+3][s] = h2h(v.w);
  }
  #pragma unroll
  for (int j=0;j<4;++j){
    int e0 = (j*256+t)*4;                           // 0..4095
    int s = e0 >> 6, p = e0 & 63;
    float sc = dtl[s] * expf(AcL - Ac[s]);
    ushort4 v = *(const ushort4*)&xBC[(size_t)(row0+s)*CONV_DIM + h*HEADDIM + p];
    xdT[p+0][s] = (_Float16)(h2f(v.x)*sc);
    xdT[p+1][s] = (_Float16)(h2f(v.y)*sc);
    xdT[p+2][s] = (_Float16)(h2f(v.z)*sc);
    xdT[p+3][s] = (_Float16)(h2f(v.w)*sc);
  }
  __syncthreads();
  const int fr = ln & 15, fk = (ln >> 4) * 8;
  f32x4 acc[4][2] = {};
  #pragma unroll
  for (int ks = 0; ks < 2; ++ks){
    half8 a[4], bb[2];
    #pragma unroll
    for (int pt=0;pt<4;++pt) a[pt] = *(const half8*)&xdT[pt*16+fr][ks*32+fk];
    #pragma unroll
    for (int nt=0;nt<2;++nt) bb[nt] = *(const half8*)&Bt[(wid*2+nt)*16+fr][ks*32+fk];
    #pragma unroll
    for (int pt=0;pt<4;++pt)
      #pragma unroll
      for (int nt=0;nt<2;++nt)
        acc[pt][nt] = __builtin_amdgcn_mfma_f32_16x16x32_f16(a[pt], bb[nt], acc[pt][nt], 0, 0, 0);
  }
  unsigned short* Sp = &states[(size_t)blk*8192];
  #pragma unroll
  for (int pt=0;pt<4;++pt){
    int p0 = pt*16 + (ln>>4)*4;
    #pragma unroll
    for (int nt=0;nt<2;++nt){
      int n = (wid*2+nt)*16 + fr;
      #pragma unroll
      for (int j=0;j<4;++j) Sp[(p0+j)*128 + n] = f2h(acc[pt][nt][j]);
    }
  }
}

// inter-chunk scan: prefetch all chunk values, then serial VALU recurrence + stores
__global__ __launch_bounds__(256) void scan_kernel(const float* __restrict__ A_cum,
                                                   unsigned short* __restrict__ states) {
  int g  = blockIdx.x & 7;
  int bh = blockIdx.x >> 3;
  int b = bh >> 5, h = bh & 31;
  int t = threadIdx.x;
  int off = g*1024 + t*4;
  ushort4 tmp[NCHUNK];
  float dec[NCHUNK];
  #pragma unroll
  for (int c=0;c<NCHUNK;++c){
    tmp[c] = *(const ushort4*)&states[(size_t)((b*32+c)*32 + h)*8192 + off];
    dec[c] = A_cum[((b*32+h)*32 + c)*64 + 63];
  }
  float s0=0.f, s1=0.f, s2=0.f, s3=0.f;
  #pragma unroll
  for (int c=0;c<NCHUNK;++c){
    float d = expf(dec[c]);
    ushort4 o; o.x=f2h(s0); o.y=f2h(s1); o.z=f2h(s2); o.w=f2h(s3);
    *(ushort4*)&states[(size_t)((b*32+c)*32 + h)*8192 + off] = o;
    s0 = s0*d + h2f(tmp[c].x);
    s1 = s1*d + h2f(tmp[c].y);
    s2 = s2*d + h2f(tmp[c].z);
    s3 = s3*d + h2f(tmp[c].w);
  }
}

// ---------- MFMA Y (fused sum-of-squares -> sc_raw via atomics) ----------
__global__ __launch_bounds__(256) void y_mfma(const unsigned short* __restrict__ xBC,
    const unsigned short* __restrict__ zx, const float* __restrict__ dt,
    const float* __restrict__ A_cum, const unsigned short* __restrict__ G,
    const unsigned short* __restrict__ states, const float* __restrict__ Dp,
    unsigned short* __restrict__ y_pre, float* __restrict__ sc_raw) {
  int blk = blockIdx.x;                             // (b*32+c)*32+h
  int h = blk & 31, c = (blk>>5)&31, b = blk>>10;
  __shared__ _Float16 Cl[64][136];
  __shared__ _Float16 Sin[64][136];
  __shared__ _Float16 Ms[64][72];
  __shared__ _Float16 xdT[64][72];
  __shared__ float Ac[64], dtl[64];
  int t = threadIdx.x;
  int wid = t >> 6, ln = t & 63;
  int row0 = b*LSEQ + c*CHUNK;
  if (t < 64){ Ac[t] = A_cum[((b*32+h)*32 + c)*64 + t]; dtl[t] = dt[(row0+t)*NHEADS + h]; }
  __syncthreads();
  #pragma unroll
  for (int j=0;j<8;++j){
    int e0 = (j*256+t)*4; int l = e0>>7, n = e0&127;
    float sc = expf(Ac[l]);
    ushort4 v = *(const ushort4*)&xBC[(size_t)(row0+l)*CONV_DIM + D_INNER + D_STATE + n];
    half4 hv = { (_Float16)(h2f(v.x)*sc), (_Float16)(h2f(v.y)*sc),
                 (_Float16)(h2f(v.z)*sc), (_Float16)(h2f(v.w)*sc) };
    *(half4*)&Cl[l][n] = hv;
  }
  {
    const unsigned short* Sg = &states[(size_t)blk*8192];
    #pragma unroll
    for (int j=0;j<8;++j){
      int elem = (j*256+t)*4; int p = elem>>7, n = elem&127;
      ushort4 v = *(const ushort4*)&Sg[elem];
      half4 hv = { h2h(v.x), h2h(v.y), h2h(v.z), h2h(v.w) };
      *(half4*)&Sin[p][n] = hv;
    }
  }
  #pragma unroll
  for (int j=0;j<4;++j){
    int e0 = (j*256+t)*4; int s = e0>>6, p = e0&63;
    float sc = dtl[s];
    ushort4 v = *(const ushort4*)&xBC[(size_t)(row0+s)*CONV_DIM + h*HEADDIM + p];
    xdT[p+0][s] = (_Float16)(h2f(v.x)*sc);
    xdT[p+1][s] = (_Float16)(h2f(v.y)*sc);
    xdT[p+2][s] = (_Float16)(h2f(v.z)*sc);
    xdT[p+3][s] = (_Float16)(h2f(v.w)*sc);
  }
  {
    const unsigned short* Gp = &G[(size_t)(b*32+c)*4096];
    #pragma unroll
    for (int j=0;j<4;++j){
      int e0 = (j*256+t)*4; int l = e0>>6, s = e0&63;
      ushort4 gv = *(const ushort4*)&Gp[e0];
      float al = Ac[l];
      Ms[l][s+0] = (s+0 <= l) ? (_Float16)(h2f(gv.x) * expf(al-Ac[s+0])) : (_Float16)0.f;
      Ms[l][s+1] = (s+1 <= l) ? (_Float16)(h2f(gv.y) * expf(al-Ac[s+1])) : (_Float16)0.f;
      Ms[l][s+2] = (s+2 <= l) ? (_Float16)(h2f(gv.z) * expf(al-Ac[s+2])) : (_Float16)0.f;
      Ms[l][s+3] = (s+3 <= l) ? (_Float16)(h2f(gv.w) * expf(al-Ac[s+3])) : (_Float16)0.f;
    }
  }
  __syncthreads();
  const int wr = wid >> 1, wc = wid & 1;
  const int fr = ln & 15, fk = (ln >> 4) * 8;
  f32x4 acc[2][2] = {};
  #pragma unroll
  for (int ks = 0; ks < 4; ++ks){
    half8 a[2], bb[2];
    #pragma unroll
    for (int lt=0;lt<2;++lt) a[lt] = *(const half8*)&Cl[(wr*2+lt)*16+fr][ks*32+fk];
    #pragma unroll
    for (int pt=0;pt<2;++pt) bb[pt] = *(const half8*)&Sin[(wc*2+pt)*16+fr][ks*32+fk];
    #pragma unroll
    for (int lt=0;lt<2;++lt)
      #pragma unroll
      for (int pt=0;pt<2;++pt)
        acc[lt][pt] = __builtin_amdgcn_mfma_f32_16x16x32_f16(a[lt], bb[pt], acc[lt][pt], 0, 0, 0);
  }
  #pragma unroll
  for (int ks = 0; ks < 2; ++ks){
    half8 a[2], bb[2];
    #pragma unroll
    for (int lt=0;lt<2;++lt) a[lt] = *(const half8*)&Ms[(wr*2+lt)*16+fr][ks*32+fk];
    #pragma unroll
    for (int pt=0;pt<2;++pt) bb[pt] = *(const half8*)&xdT[(wc*2+pt)*16+fr][ks*32+fk];
    #pragma unroll
    for (int lt=0;lt<2;++lt)
      #pragma unroll
      for (int pt=0;pt<2;++pt)
        acc[lt][pt] = __builtin_amdgcn_mfma_f32_16x16x32_f16(a[lt], bb[pt], acc[lt][pt], 0, 0, 0);
  }
  float Dh = Dp[h];
  #pragma unroll
  for (int lt=0;lt<2;++lt){
    int l0 = (wr*2+lt)*16 + (ln>>4)*4;
    #pragma unroll
    for (int j=0;j<4;++j){
      int grow = row0 + l0 + j;
      float s = 0.f;
      #pragma unroll
      for (int pt=0;pt<2;++pt){
        int p = (wc*2+pt)*16 + fr;
        float x = h2f(xBC[(size_t)grow*CONV_DIM + h*HEADDIM + p]);
        float z = h2f(zx[(size_t)grow*DPROJ + h*HEADDIM + p]);
        float yv = (acc[lt][pt][j] + x*Dh) * siluf(z);
        y_pre[(size_t)grow*D_INNER + h*HEADDIM + p] = f2h(yv);
        s += yv*yv;
      }
      // reduce across the 16 lanes sharing this row (fr bits), then one atomic
      s += __shfl_xor(s, 1, 64);
      s += __shfl_xor(s, 2, 64);
      s += __shfl_xor(s, 4, 64);
      s += __shfl_xor(s, 8, 64);
      if (fr == 0) atomicAdd(&sc_raw[grow], s);
    }
  }
}

extern "C" void kernel_launch(void* const* d_in, const int* in_sizes, int n_in,
                              void* d_out, int out_size, void* d_ws, size_t ws_size,
                              hipStream_t stream) {
  const float* u       = (const float*)d_in[0];
  const float* W_in    = (const float*)d_in[1];
  const float* conv_w  = (const float*)d_in[2];
  const float* conv_b  = (const float*)d_in[3];
  const float* dt_bias = (const float*)d_in[4];
  const float* A_log   = (const float*)d_in[5];
  const float* Dp      = (const float*)d_in[6];
  const float* norm_w  = (const float*)d_in[7];
  const float* W_out   = (const float*)d_in[8];
  float* out = (float*)d_out;

  char* w = (char*)d_ws;
  unsigned short* zx_h   = (unsigned short*)w;  w += (size_t)BL*DPROJ*2;
  unsigned short* xBC_h  = (unsigned short*)w;  w += (size_t)BL*CONV_DIM*2;
  unsigned short* ypre_h = (unsigned short*)w;  w += (size_t)BL*D_INNER*2;
  unsigned short* u_h    = (unsigned short*)w;  w += (size_t)BL*D_MODEL*2;
  unsigned short* Win_h  = (unsigned short*)w;  w += (size_t)NPAD1*D_MODEL*2;
  unsigned short* Wg_h   = (unsigned short*)w;  w += (size_t)D_MODEL*D_INNER*2;
  unsigned short* states = (unsigned short*)w;  w += (size_t)B_SZ*NCHUNK*NHEADS*HEADDIM*D_STATE*2;
  unsigned short* G      = (unsigned short*)w;  w += (size_t)B_SZ*NCHUNK*CHUNK*CHUNK*2;
  float* dt     = (float*)w;  w += (size_t)BL*NHEADS*4;
  float* A_cum  = (float*)w;  w += (size_t)B_SZ*NHEADS*NCHUNK*CHUNK*4;
  float* sc_raw = (float*)w;  w += (size_t)BL*4;

  // 0) all converts in one launch (Wg = W_out * norm_w, RMS fold)
  cvt_all<<<(NCVT+255)/256, 256, 0, stream>>>(u, W_in, W_out, norm_w, u_h, Win_h, Wg_h);
  // 1) zxbcdt = u @ W_in.T  (fp16 out; includes dt logit columns)
  gemm_f16_pipe<1><<<dim3(NPAD1/128, BL/128), 256, 0, stream>>>(u_h, Win_h, zx_h, nullptr, DPROJ, D_MODEL);
  // 2) dt + per-chunk cumsum (fused) + zero sc_raw
  dtacum_kernel<<<B_SZ*NHEADS*NCHUNK, 64, 0, stream>>>(zx_h, dt_bias, A_log, dt, A_cum, sc_raw);
  // 3) depthwise conv + silu (16 rows/thread)
  conv16_kernel<<<((BL/16)*(CONV_DIM/4)+255)/256, 256, 0, stream>>>(zx_h, conv_w, conv_b, xBC_h);
  // 4) G = C B^T per (b,c), fp16 out
  g_kernel<<<B_SZ*NCHUNK*4, 256, 0, stream>>>(xBC_h, G);
  // 5) per-chunk states (MFMA, fp16 out)
  states_mfma<<<B_SZ*NCHUNK*NHEADS, 256, 0, stream>>>(xBC_h, dt, A_cum, states);
  // 6) inter-chunk scan (prefetch-all + serial recurrence), 8-way split
  scan_kernel<<<B_SZ*NHEADS*8, 256, 0, stream>>>(A_cum, states);
  // 7) Y (MFMA), fp16 out + fused sum-of-squares into sc_raw
  y_mfma<<<B_SZ*NCHUNK*NHEADS, 256, 0, stream>>>(xBC_h, zx_h, dt, A_cum, G, states, Dp, ypre_h, sc_raw);
  // 8) out = rsqrt(mean sq) * (ypre @ (W_out*norm_w).T)  (RMS fully fused into GEMM2)
  gemm_f16_64<<<dim3(D_MODEL/128, BL/64), 256, 0, stream>>>(ypre_h, Wg_h, out, sc_raw, D_MODEL, D_INNER);
}

// Round 18
// 185.492 us; speedup vs baseline: 1.0627x; 1.0627x over previous
//
#include <hip/hip_runtime.h>
#include <hip/hip_bf16.h>
#include <math.h>

#define D_MODEL 1024
#define D_INNER 2048
#define D_STATE 128
#define NHEADS 32
#define HEADDIM 64
#define CHUNK 64
#define B_SZ 2
#define LSEQ 2048
#define BL (B_SZ*LSEQ)                              // 4096
#define DPROJ (2*D_INNER + 2*D_STATE + NHEADS)      // 4384
#define CONV_DIM (D_INNER + 2*D_STATE)              // 2304
#define NCHUNK (LSEQ/CHUNK)                         // 32
#define NPAD1 4480                                  // DPROJ padded to x128
#define EPSF 1e-5f

typedef __attribute__((ext_vector_type(8))) _Float16 half8;
typedef __attribute__((ext_vector_type(4))) _Float16 half4;
typedef __attribute__((ext_vector_type(4))) float f32x4;

__device__ __forceinline__ float siluf(float v){ return v / (1.0f + expf(-v)); }
__device__ __forceinline__ float softplusf(float v){ return v > 20.0f ? v : log1pf(expf(v)); }
__device__ __forceinline__ unsigned short f2h(float x){
  union { _Float16 h; unsigned short u; } v; v.h = (_Float16)x;
  return v.u;
}
__device__ __forceinline__ float h2f(unsigned short x){
  union { unsigned short u; _Float16 h; } v; v.u = x;
  return (float)v.h;
}
__device__ __forceinline__ _Float16 h2h(unsigned short x){
  union { unsigned short u; _Float16 h; } v; v.u = x;
  return v.h;
}

typedef const __attribute__((address_space(1))) void gvoid_t;
typedef __attribute__((address_space(3))) void lvoid_t;
__device__ __forceinline__ void gl_lds16(const void* gsrc, void* ldst) {
  gvoid_t* g = reinterpret_cast<gvoid_t*>((uintptr_t)gsrc);
  lvoid_t* l = reinterpret_cast<lvoid_t*>((unsigned int)(uintptr_t)ldst);
  __builtin_amdgcn_global_load_lds(g, l, 16, 0, 0);
}

#define NU4  (BL*D_MODEL/4)
#define NW4  (NPAD1*D_MODEL/4)
#define NWo4 (D_MODEL*D_INNER/4)
#define NCVT (NU4+NW4+NWo4)

// ---------- fused converters ----------
__global__ void cvt_all(const float* __restrict__ u, const float* __restrict__ W_in,
                        const float* __restrict__ W_out, const float* __restrict__ norm_w,
                        unsigned short* __restrict__ u_h, unsigned short* __restrict__ Win_h,
                        unsigned short* __restrict__ Wg_h) {
  int i = blockIdx.x*256 + threadIdx.x;
  if (i >= NCVT) return;
  if (i < NU4) {
    float4 v = *(const float4*)(u + (size_t)i*4);
    ushort4 o; o.x=f2h(v.x); o.y=f2h(v.y); o.z=f2h(v.z); o.w=f2h(v.w);
    *(ushort4*)(u_h + (size_t)i*4) = o;
  } else if (i < NU4 + NW4) {
    int q = i - NU4;
    int row = q / (D_MODEL/4);
    ushort4 o; o.x=0; o.y=0; o.z=0; o.w=0;
    if (row < DPROJ) {
      float4 v = *(const float4*)(W_in + (size_t)q*4);
      o.x=f2h(v.x); o.y=f2h(v.y); o.z=f2h(v.z); o.w=f2h(v.w);
    }
    *(ushort4*)(Win_h + (size_t)q*4) = o;
  } else {
    int q = i - NU4 - NW4;
    int colq = q % (D_INNER/4);
    float4 v = *(const float4*)(W_out + (size_t)q*4);
    float4 g = *(const float4*)(norm_w + (size_t)colq*4);
    ushort4 o; o.x=f2h(v.x*g.x); o.y=f2h(v.y*g.y); o.z=f2h(v.z*g.z); o.w=f2h(v.w*g.w);
    *(ushort4*)(Wg_h + (size_t)q*4) = o;
  }
}

// ---------- GEMM1: 128x128, 4 slots, 2 K-tiles per barrier pair, region-mapped ----------
template<int OUT_F16>
__global__ __launch_bounds__(256) void gemm_f16_pipe(const unsigned short* __restrict__ A,
    const unsigned short* __restrict__ W, void* __restrict__ Cv,
    const float* __restrict__ Sc, int N, int K) {
  __shared__ unsigned short lds[4*2*4096];          // 64 KB -> 2 blocks/CU
  const int t   = threadIdx.x;
  const int wid = t >> 6, l = t & 63;
  const int gx = gridDim.x, gy = gridDim.y;         // gy % 8 == 0
  int bid = blockIdx.y * gx + blockIdx.x;
  int k   = bid & 7;
  int j   = bid >> 3;
  int rpx = gy >> 3;
  int r   = j % rpx;
  int colIdx = j / rpx;
  int row = k*rpx + r;
  int col = (colIdx + k*(gx >> 3)) % gx;
  const int m0 = row * 128;
  const int n0 = col * 128;
  const int wr = wid >> 1, wc = wid & 1;
  const int fr = l & 15, cg = l >> 4;
  const int NT = K >> 5;

  int srow[2]; int scol[2];
  #pragma unroll
  for (int i=0;i<2;++i){
    int s = i*256 + t;
    int rr = s >> 2, c = s & 3;
    int sw = (rr + (rr>>2)) & 3;
    srow[i] = rr; scol[i] = (c ^ sw) * 8;
  }
  const unsigned short* Abase = A + (size_t)m0 * K;
  const unsigned short* Wbase = W + (size_t)n0 * K;

#define STAGE(tt, slot) { \
    int kk = (tt) << 5; \
    unsigned short* La = &lds[(slot)*8192]; \
    unsigned short* Lb = &lds[(slot)*8192 + 4096]; \
    gl_lds16(Abase + (size_t)srow[0]*K + kk + scol[0], (char*)La + (0*256+t)*16); \
    gl_lds16(Abase + (size_t)srow[1]*K + kk + scol[1], (char*)La + (1*256+t)*16); \
    gl_lds16(Wbase + (size_t)srow[0]*K + kk + scol[0], (char*)Lb + (0*256+t)*16); \
    gl_lds16(Wbase + (size_t)srow[1]*K + kk + scol[1], (char*)Lb + (1*256+t)*16); \
  }

#define COMPUTE(slot) { \
    const unsigned short* La = &lds[(slot)*8192]; \
    const unsigned short* Lb = &lds[(slot)*8192 + 4096]; \
    half8 af[4], bfv[4]; \
    _Pragma("unroll") \
    for (int m=0;m<4;++m){ \
      int rr = wr*64 + m*16 + fr; \
      int sw = (rr + (rr>>2)) & 3; \
      af[m] = *(const half8*)&La[(rr*4 + (cg ^ sw))*8]; \
    } \
    _Pragma("unroll") \
    for (int n=0;n<4;++n){ \
      int rr = wc*64 + n*16 + fr; \
      int sw = (rr + (rr>>2)) & 3; \
      bfv[n] = *(const half8*)&Lb[(rr*4 + (cg ^ sw))*8]; \
    } \
    __builtin_amdgcn_s_setprio(1); \
    _Pragma("unroll") \
    for (int m=0;m<4;++m) \
      _Pragma("unroll") \
      for (int n=0;n<4;++n) \
        acc[m][n] = __builtin_amdgcn_mfma_f32_16x16x32_f16(af[m], bfv[n], acc[m][n], 0, 0, 0); \
    __builtin_amdgcn_s_setprio(0); \
  }

  f32x4 acc[4][4] = {};
  STAGE(0, 0);
  STAGE(1, 1);
  STAGE(2, 2);
  STAGE(3, 3);

  for (int tt = 0; tt < NT; tt += 2) {
    if (tt + 4 < NT) { asm volatile("s_waitcnt vmcnt(8)" ::: "memory"); }
    else             { asm volatile("s_waitcnt vmcnt(0)" ::: "memory"); }
    __builtin_amdgcn_s_barrier();
    asm volatile("" ::: "memory");

    COMPUTE(tt & 3);
    COMPUTE((tt + 1) & 3);

    asm volatile("s_waitcnt lgkmcnt(0)" ::: "memory");
    __builtin_amdgcn_s_barrier();
    asm volatile("" ::: "memory");
    if (tt + 4 < NT) {
      STAGE(tt + 4, (tt + 4) & 3);
      if (tt + 5 < NT) STAGE(tt + 5, (tt + 5) & 3);
    }
  }
#undef COMPUTE
#undef STAGE

  const int crow = m0 + wr*64 + (l >> 4) * 4;
  const int ccol0 = n0 + wc*64 + fr;
  #pragma unroll
  for (int m = 0; m < 4; ++m) {
    #pragma unroll
    for (int n = 0; n < 4; ++n) {
      int colo = ccol0 + n*16;
      if (colo < N) {
        if (OUT_F16) {
          unsigned short* cp = (unsigned short*)Cv + (size_t)(crow + m*16)*N + colo;
          #pragma unroll
          for (int jj = 0; jj < 4; ++jj) cp[(size_t)jj*N] = f2h(acc[m][n][jj]);
        } else {
          float* cp = (float*)Cv + (size_t)(crow + m*16)*N + colo;
          #pragma unroll
          for (int jj = 0; jj < 4; ++jj) cp[(size_t)jj*N] = acc[m][n][jj] * Sc[crow + m*16 + jj];
        }
      }
    }
  }
}

// ---------- GEMM2: 64x128 tile, 4 waves, 48 KB LDS -> 3 blocks/CU, pair schedule ----------
__global__ __launch_bounds__(256) void gemm_f16_64(const unsigned short* __restrict__ A,
    const unsigned short* __restrict__ W, float* __restrict__ C,
    const float* __restrict__ Sc, int N, int K) {
  __shared__ unsigned short lds[4*6144];            // 4 slots x 12KB = 48KB
  const int t   = threadIdx.x;
  const int wid = t >> 6, l = t & 63;
  const int gx = gridDim.x, gy = gridDim.y;         // 8 x 64
  int bid = blockIdx.y * gx + blockIdx.x;
  int k   = bid & 7;
  int j   = bid >> 3;
  int rpx = gy >> 3;                                // 8
  int r   = j % rpx;
  int colIdx = j / rpx;
  const int m0 = (k*rpx + r) * 64;
  const int n0 = ((colIdx + k*(gx >> 3)) % gx) * 128;
  const int fr = l & 15, cg = l >> 4;
  const int NT = K >> 5;                            // 64 (even)

  const int srw  = t >> 2;
  const int sw_  = (srw + (srw>>2)) & 3;            // sw(r) == sw(r+64)
  const int scl  = ((t & 3) ^ sw_) * 8;
  const unsigned short* Abase = A + (size_t)m0 * K;
  const unsigned short* Wbase = W + (size_t)n0 * K;

#define STG64(tt, slot) { \
    int kk = (tt) << 5; \
    char* Ls = (char*)lds + (slot)*12288; \
    gl_lds16(Abase + (size_t)srw*K + kk + scl,        Ls + t*16); \
    gl_lds16(Wbase + (size_t)srw*K + kk + scl,        Ls + 4096 + t*16); \
    gl_lds16(Wbase + (size_t)(64+srw)*K + kk + scl,   Ls + 4096 + (256+t)*16); \
  }

#define CMP64(slot) { \
    const unsigned short* La = &lds[(slot)*6144]; \
    const unsigned short* Lb = &lds[(slot)*6144 + 2048]; \
    half8 af[4], bfv[2]; \
    _Pragma("unroll") \
    for (int m=0;m<4;++m){ \
      int rr = m*16 + fr; \
      int sw = (rr + (rr>>2)) & 3; \
      af[m] = *(const half8*)&La[(rr*4 + (cg ^ sw))*8]; \
    } \
    _Pragma("unroll") \
    for (int n=0;n<2;++n){ \
      int rr = wid*32 + n*16 + fr; \
      int sw = (rr + (rr>>2)) & 3; \
      bfv[n] = *(const half8*)&Lb[(rr*4 + (cg ^ sw))*8]; \
    } \
    __builtin_amdgcn_s_setprio(1); \
    _Pragma("unroll") \
    for (int m=0;m<4;++m) \
      _Pragma("unroll") \
      for (int n=0;n<2;++n) \
        acc[m][n] = __builtin_amdgcn_mfma_f32_16x16x32_f16(af[m], bfv[n], acc[m][n], 0, 0, 0); \
    __builtin_amdgcn_s_setprio(0); \
  }

  f32x4 acc[4][2] = {};
  STG64(0, 0);
  STG64(1, 1);
  STG64(2, 2);
  STG64(3, 3);

  for (int tt = 0; tt < NT; tt += 2) {
    if (tt + 4 < NT) { asm volatile("s_waitcnt vmcnt(6)" ::: "memory"); }
    else             { asm volatile("s_waitcnt vmcnt(0)" ::: "memory"); }
    __builtin_amdgcn_s_barrier();
    asm volatile("" ::: "memory");

    CMP64(tt & 3);
    CMP64((tt + 1) & 3);

    asm volatile("s_waitcnt lgkmcnt(0)" ::: "memory");
    __builtin_amdgcn_s_barrier();
    asm volatile("" ::: "memory");
    if (tt + 4 < NT) {
      STG64(tt + 4, (tt + 4) & 3);
      if (tt + 5 < NT) STG64(tt + 5, (tt + 5) & 3);
    }
  }
#undef CMP64
#undef STG64

  const int crow = m0 + cg * 4;
  const int ccol0 = n0 + wid*32 + fr;
  #pragma unroll
  for (int m = 0; m < 4; ++m) {
    #pragma unroll
    for (int n = 0; n < 2; ++n) {
      int colo = ccol0 + n*16;
      float* cp = C + (size_t)(crow + m*16)*N + colo;
      #pragma unroll
      for (int jj = 0; jj < 4; ++jj) cp[(size_t)jj*N] = acc[m][n][jj] * Sc[crow + m*16 + jj];
    }
  }
}

// ---------- fused dt + per-chunk cumsum ----------
__global__ __launch_bounds__(64) void dtacum_kernel(const unsigned short* __restrict__ zx,
    const float* __restrict__ dt_bias, const float* __restrict__ A_log,
    float* __restrict__ dt, float* __restrict__ A_cum) {
  int blk = blockIdx.x;                             // (b*32+h)*32+c
  int c = blk & 31, h = (blk >> 5) & 31, b = blk >> 10;
  int l = threadIdx.x;
  int row = b*LSEQ + c*CHUNK + l;
  float v = h2f(zx[(size_t)row*DPROJ + (2*D_INNER + 2*D_STATE) + h]) + dt_bias[h];
  float dtv = softplusf(v);
  dt[row*NHEADS + h] = dtv;
  float val = -expf(A_log[h]) * dtv;
  #pragma unroll
  for (int off = 1; off < 64; off <<= 1) {
    float nv = __shfl_up(val, off, 64);
    if (l >= off) val += nv;
  }
  A_cum[blk*64 + l] = val;
}

// causal depthwise conv (K=4) + bias + silu; fp16 in/out; 8 rows x 4 channels per thread
__global__ __launch_bounds__(256) void conv8_kernel(const unsigned short* __restrict__ zx,
    const float* __restrict__ w, const float* __restrict__ bias, unsigned short* __restrict__ xBC) {
  int idx = blockIdx.x*256 + threadIdx.x;           // over (BL/8) * (CONV_DIM/4)
  if (idx >= (BL/8)*(CONV_DIM/4)) return;
  int c4  = idx % (CONV_DIM/4);
  int rb  = idx / (CONV_DIM/4);
  int ch  = c4 * 4;
  int row0 = rb * 8;
  int l0   = row0 & (LSEQ-1);
  float4 r[11];
  #pragma unroll
  for (int jj=0;jj<11;++jj){
    int li = l0 + jj - 3;
    if (li >= 0) {
      ushort4 v = *(const ushort4*)&zx[(size_t)(row0 + jj - 3)*DPROJ + D_INNER + ch];
      r[jj] = make_float4(h2f(v.x), h2f(v.y), h2f(v.z), h2f(v.w));
    } else r[jj] = make_float4(0.f,0.f,0.f,0.f);
  }
  float4 wv[4];
  #pragma unroll
  for (int c=0;c<4;++c) wv[c] = *(const float4*)&w[(ch+c)*4];
  float4 bv = *(const float4*)&bias[ch];
  #pragma unroll
  for (int j=0;j<8;++j){
    float4 acc = bv;
    acc.x += wv[0].x*r[j].x + wv[0].y*r[j+1].x + wv[0].z*r[j+2].x + wv[0].w*r[j+3].x;
    acc.y += wv[1].x*r[j].y + wv[1].y*r[j+1].y + wv[1].z*r[j+2].y + wv[1].w*r[j+3].y;
    acc.z += wv[2].x*r[j].z + wv[2].y*r[j+1].z + wv[2].z*r[j+2].z + wv[2].w*r[j+3].z;
    acc.w += wv[3].x*r[j].w + wv[3].y*r[j+1].w + wv[3].z*r[j+2].w + wv[3].w*r[j+3].w;
    ushort4 o; o.x=f2h(siluf(acc.x)); o.y=f2h(siluf(acc.y)); o.z=f2h(siluf(acc.z)); o.w=f2h(siluf(acc.w));
    *(ushort4*)&xBC[(size_t)(row0+j)*CONV_DIM + ch] = o;
  }
}

// G[b,c][l][s] = sum_n C[l,n] * B[s,n]; 4 blocks per (b,c); fp16 G out
__global__ __launch_bounds__(256) void g_kernel(const unsigned short* __restrict__ xBC,
                                                unsigned short* __restrict__ G) {
  int blk = blockIdx.x >> 2;                        // b*32 + c
  int lq  = blockIdx.x & 3;
  int b = blk >> 5, c = blk & 31;
  __shared__ float Bsh[64][129];
  int t = threadIdx.x;
  int row0 = b*LSEQ + c*CHUNK;
  #pragma unroll
  for (int j=0;j<8;++j){
    int e0 = (j*256 + t)*4;                         // 0..8191
    int s = e0 >> 7, n = e0 & 127;
    ushort4 v = *(const ushort4*)&xBC[(size_t)(row0+s)*CONV_DIM + D_INNER + n];
    Bsh[s][n+0] = h2f(v.x); Bsh[s][n+1] = h2f(v.y);
    Bsh[s][n+2] = h2f(v.z); Bsh[s][n+3] = h2f(v.w);
  }
  __syncthreads();
  int l = lq*16 + (t >> 4), s0 = (t & 15) * 4;
  const unsigned short* Cp = &xBC[(size_t)(row0+l)*CONV_DIM + D_INNER + D_STATE];
  float acc[4] = {};
  #pragma unroll 4
  for (int n4=0;n4<32;++n4){
    ushort4 cv4 = *(const ushort4*)&Cp[n4*4];
    float cv[4] = { h2f(cv4.x), h2f(cv4.y), h2f(cv4.z), h2f(cv4.w) };
    #pragma unroll
    for (int kk=0;kk<4;++kk){
      #pragma unroll
      for (int j=0;j<4;++j) acc[j] += cv[kk] * Bsh[s0+j][n4*4+kk];
    }
  }
  unsigned short* Gp = &G[(size_t)blk*4096 + l*64 + s0];
  ushort4 o; o.x=f2h(acc[0]); o.y=f2h(acc[1]); o.z=f2h(acc[2]); o.w=f2h(acc[3]);
  *(ushort4*)Gp = o;
}

// ---------- MFMA states (fp16 out, vectorized staging) ----------
__global__ __launch_bounds__(256) void states_mfma(const unsigned short* __restrict__ xBC,
    const float* __restrict__ dt, const float* __restrict__ A_cum, unsigned short* __restrict__ states) {
  int blk = blockIdx.x;                             // (b*32+c)*32+h
  int h = blk & 31, c = (blk>>5)&31, b = blk>>10;
  __shared__ _Float16 Bt[128][72];                  // [n][s]
  __shared__ _Float16 xdT[64][72];                  // [p][s]
  __shared__ float Ac[64], dtl[64];
  int t = threadIdx.x;
  int wid = t >> 6, ln = t & 63;
  int row0 = b*LSEQ + c*CHUNK;
  if (t < 64){ Ac[t] = A_cum[((b*32+h)*32 + c)*64 + t]; dtl[t] = dt[(row0+t)*NHEADS + h]; }
  __syncthreads();
  float AcL = Ac[63];
  #pragma unroll
  for (int j=0;j<8;++j){
    int e0 = (j*256+t)*4;                           // 0..8191
    int s = e0 >> 7, n = e0 & 127;
    ushort4 v = *(const ushort4*)&xBC[(size_t)(row0+s)*CONV_DIM + D_INNER + n];
    Bt[n+0][s] = h2h(v.x); Bt[n+1][s] = h2h(v.y);
    Bt[n+2][s] = h2h(v.z); Bt[n+3][s] = h2h(v.w);
  }
  #pragma unroll
  for (int j=0;j<4;++j){
    int e0 = (j*256+t)*4;                           // 0..4095
    int s = e0 >> 6, p = e0 & 63;
    float sc = dtl[s] * expf(AcL - Ac[s]);
    ushort4 v = *(const ushort4*)&xBC[(size_t)(row0+s)*CONV_DIM + h*HEADDIM + p];
    xdT[p+0][s] = (_Float16)(h2f(v.x)*sc);
    xdT[p+1][s] = (_Float16)(h2f(v.y)*sc);
    xdT[p+2][s] = (_Float16)(h2f(v.z)*sc);
    xdT[p+3][s] = (_Float16)(h2f(v.w)*sc);
  }
  __syncthreads();
  const int fr = ln & 15, fk = (ln >> 4) * 8;
  f32x4 acc[4][2] = {};
  #pragma unroll
  for (int ks = 0; ks < 2; ++ks){
    half8 a[4], bb[2];
    #pragma unroll
    for (int pt=0;pt<4;++pt) a[pt] = *(const half8*)&xdT[pt*16+fr][ks*32+fk];
    #pragma unroll
    for (int nt=0;nt<2;++nt) bb[nt] = *(const half8*)&Bt[(wid*2+nt)*16+fr][ks*32+fk];
    #pragma unroll
    for (int pt=0;pt<4;++pt)
      #pragma unroll
      for (int nt=0;nt<2;++nt)
        acc[pt][nt] = __builtin_amdgcn_mfma_f32_16x16x32_f16(a[pt], bb[nt], acc[pt][nt], 0, 0, 0);
  }
  unsigned short* Sp = &states[(size_t)blk*8192];
  #pragma unroll
  for (int pt=0;pt<4;++pt){
    int p0 = pt*16 + (ln>>4)*4;
    #pragma unroll
    for (int nt=0;nt<2;++nt){
      int n = (wid*2+nt)*16 + fr;
      #pragma unroll
      for (int j=0;j<4;++j) Sp[(p0+j)*128 + n] = f2h(acc[pt][nt][j]);
    }
  }
}

// inter-chunk scan: prefetch all chunk values, then serial VALU recurrence + stores
__global__ __launch_bounds__(256) void scan_kernel(const float* __restrict__ A_cum,
                                                   unsigned short* __restrict__ states) {
  int g  = blockIdx.x & 7;
  int bh = blockIdx.x >> 3;
  int b = bh >> 5, h = bh & 31;
  int t = threadIdx.x;
  int off = g*1024 + t*4;
  ushort4 tmp[NCHUNK];
  float dec[NCHUNK];
  #pragma unroll
  for (int c=0;c<NCHUNK;++c){
    tmp[c] = *(const ushort4*)&states[(size_t)((b*32+c)*32 + h)*8192 + off];
    dec[c] = A_cum[((b*32+h)*32 + c)*64 + 63];
  }
  float s0=0.f, s1=0.f, s2=0.f, s3=0.f;
  #pragma unroll
  for (int c=0;c<NCHUNK;++c){
    float d = expf(dec[c]);
    ushort4 o; o.x=f2h(s0); o.y=f2h(s1); o.z=f2h(s2); o.w=f2h(s3);
    *(ushort4*)&states[(size_t)((b*32+c)*32 + h)*8192 + off] = o;
    s0 = s0*d + h2f(tmp[c].x);
    s1 = s1*d + h2f(tmp[c].y);
    s2 = s2*d + h2f(tmp[c].z);
    s3 = s3*d + h2f(tmp[c].w);
  }
}

// ---------- MFMA Y (vectorized staging, fp16 G) ----------
__global__ __launch_bounds__(256) void y_mfma(const unsigned short* __restrict__ xBC,
    const unsigned short* __restrict__ zx, const float* __restrict__ dt,
    const float* __restrict__ A_cum, const unsigned short* __restrict__ G,
    const unsigned short* __restrict__ states, const float* __restrict__ Dp,
    unsigned short* __restrict__ y_pre) {
  int blk = blockIdx.x;                             // (b*32+c)*32+h
  int h = blk & 31, c = (blk>>5)&31, b = blk>>10;
  __shared__ _Float16 Cl[64][136];
  __shared__ _Float16 Sin[64][136];
  __shared__ _Float16 Ms[64][72];
  __shared__ _Float16 xdT[64][72];
  __shared__ float Ac[64], dtl[64];
  int t = threadIdx.x;
  int wid = t >> 6, ln = t & 63;
  int row0 = b*LSEQ + c*CHUNK;
  if (t < 64){ Ac[t] = A_cum[((b*32+h)*32 + c)*64 + t]; dtl[t] = dt[(row0+t)*NHEADS + h]; }
  __syncthreads();
  #pragma unroll
  for (int j=0;j<8;++j){
    int e0 = (j*256+t)*4; int l = e0>>7, n = e0&127;
    float sc = expf(Ac[l]);
    ushort4 v = *(const ushort4*)&xBC[(size_t)(row0+l)*CONV_DIM + D_INNER + D_STATE + n];
    half4 hv = { (_Float16)(h2f(v.x)*sc), (_Float16)(h2f(v.y)*sc),
                 (_Float16)(h2f(v.z)*sc), (_Float16)(h2f(v.w)*sc) };
    *(half4*)&Cl[l][n] = hv;
  }
  {
    const unsigned short* Sg = &states[(size_t)blk*8192];
    #pragma unroll
    for (int j=0;j<8;++j){
      int elem = (j*256+t)*4; int p = elem>>7, n = elem&127;
      ushort4 v = *(const ushort4*)&Sg[elem];
      half4 hv = { h2h(v.x), h2h(v.y), h2h(v.z), h2h(v.w) };
      *(half4*)&Sin[p][n] = hv;
    }
  }
  #pragma unroll
  for (int j=0;j<4;++j){
    int e0 = (j*256+t)*4; int s = e0>>6, p = e0&63;
    float sc = dtl[s];
    ushort4 v = *(const ushort4*)&xBC[(size_t)(row0+s)*CONV_DIM + h*HEADDIM + p];
    xdT[p+0][s] = (_Float16)(h2f(v.x)*sc);
    xdT[p+1][s] = (_Float16)(h2f(v.y)*sc);
    xdT[p+2][s] = (_Float16)(h2f(v.z)*sc);
    xdT[p+3][s] = (_Float16)(h2f(v.w)*sc);
  }
  {
    const unsigned short* Gp = &G[(size_t)(b*32+c)*4096];
    #pragma unroll
    for (int j=0;j<4;++j){
      int e0 = (j*256+t)*4; int l = e0>>6, s = e0&63;
      ushort4 gv = *(const ushort4*)&Gp[e0];
      float al = Ac[l];
      Ms[l][s+0] = (s+0 <= l) ? (_Float16)(h2f(gv.x) * expf(al-Ac[s+0])) : (_Float16)0.f;
      Ms[l][s+1] = (s+1 <= l) ? (_Float16)(h2f(gv.y) * expf(al-Ac[s+1])) : (_Float16)0.f;
      Ms[l][s+2] = (s+2 <= l) ? (_Float16)(h2f(gv.z) * expf(al-Ac[s+2])) : (_Float16)0.f;
      Ms[l][s+3] = (s+3 <= l) ? (_Float16)(h2f(gv.w) * expf(al-Ac[s+3])) : (_Float16)0.f;
    }
  }
  __syncthreads();
  const int wr = wid >> 1, wc = wid & 1;
  const int fr = ln & 15, fk = (ln >> 4) * 8;
  f32x4 acc[2][2] = {};
  #pragma unroll
  for (int ks = 0; ks < 4; ++ks){
    half8 a[2], bb[2];
    #pragma unroll
    for (int lt=0;lt<2;++lt) a[lt] = *(const half8*)&Cl[(wr*2+lt)*16+fr][ks*32+fk];
    #pragma unroll
    for (int pt=0;pt<2;++pt) bb[pt] = *(const half8*)&Sin[(wc*2+pt)*16+fr][ks*32+fk];
    #pragma unroll
    for (int lt=0;lt<2;++lt)
      #pragma unroll
      for (int pt=0;pt<2;++pt)
        acc[lt][pt] = __builtin_amdgcn_mfma_f32_16x16x32_f16(a[lt], bb[pt], acc[lt][pt], 0, 0, 0);
  }
  #pragma unroll
  for (int ks = 0; ks < 2; ++ks){
    half8 a[2], bb[2];
    #pragma unroll
    for (int lt=0;lt<2;++lt) a[lt] = *(const half8*)&Ms[(wr*2+lt)*16+fr][ks*32+fk];
    #pragma unroll
    for (int pt=0;pt<2;++pt) bb[pt] = *(const half8*)&xdT[(wc*2+pt)*16+fr][ks*32+fk];
    #pragma unroll
    for (int lt=0;lt<2;++lt)
      #pragma unroll
      for (int pt=0;pt<2;++pt)
        acc[lt][pt] = __builtin_amdgcn_mfma_f32_16x16x32_f16(a[lt], bb[pt], acc[lt][pt], 0, 0, 0);
  }
  float Dh = Dp[h];
  #pragma unroll
  for (int lt=0;lt<2;++lt){
    int l0 = (wr*2+lt)*16 + (ln>>4)*4;
    #pragma unroll
    for (int pt=0;pt<2;++pt){
      int p = (wc*2+pt)*16 + fr;
      #pragma unroll
      for (int j=0;j<4;++j){
        int grow = row0 + l0 + j;
        float x = h2f(xBC[(size_t)grow*CONV_DIM + h*HEADDIM + p]);
        float z = h2f(zx[(size_t)grow*DPROJ + h*HEADDIM + p]);
        y_pre[(size_t)grow*D_INNER + h*HEADDIM + p] = f2h((acc[lt][pt][j] + x*Dh) * siluf(z));
      }
    }
  }
}

// per-row RMS scale: sc[row] = rsqrt(mean(ypre^2) + eps)
__global__ __launch_bounds__(256) void rowsc_kernel(const unsigned short* __restrict__ y,
                                                    float* __restrict__ sc) {
  int row = blockIdx.x;
  int t = threadIdx.x;
  const unsigned short* yr = y + (size_t)row*D_INNER + t*8;
  ushort4 a = *(const ushort4*)yr;
  ushort4 bq = *(const ushort4*)(yr+4);
  float ss = 0.f;
  float v;
  v=h2f(a.x); ss+=v*v; v=h2f(a.y); ss+=v*v; v=h2f(a.z); ss+=v*v; v=h2f(a.w); ss+=v*v;
  v=h2f(bq.x); ss+=v*v; v=h2f(bq.y); ss+=v*v; v=h2f(bq.z); ss+=v*v; v=h2f(bq.w); ss+=v*v;
  #pragma unroll
  for (int off=32; off>0; off>>=1) ss += __shfl_down(ss, off, 64);
  __shared__ float wsum[4];
  int wid = t >> 6, lane = t & 63;
  if (lane == 0) wsum[wid] = ss;
  __syncthreads();
  if (t == 0) sc[row] = rsqrtf((wsum[0]+wsum[1]+wsum[2]+wsum[3])/D_INNER + EPSF);
}

extern "C" void kernel_launch(void* const* d_in, const int* in_sizes, int n_in,
                              void* d_out, int out_size, void* d_ws, size_t ws_size,
                              hipStream_t stream) {
  const float* u       = (const float*)d_in[0];
  const float* W_in    = (const float*)d_in[1];
  const float* conv_w  = (const float*)d_in[2];
  const float* conv_b  = (const float*)d_in[3];
  const float* dt_bias = (const float*)d_in[4];
  const float* A_log   = (const float*)d_in[5];
  const float* Dp      = (const float*)d_in[6];
  const float* norm_w  = (const float*)d_in[7];
  const float* W_out   = (const float*)d_in[8];
  float* out = (float*)d_out;

  char* w = (char*)d_ws;
  unsigned short* zx_h   = (unsigned short*)w;  w += (size_t)BL*DPROJ*2;
  unsigned short* xBC_h  = (unsigned short*)w;  w += (size_t)BL*CONV_DIM*2;
  unsigned short* ypre_h = (unsigned short*)w;  w += (size_t)BL*D_INNER*2;
  unsigned short* u_h    = (unsigned short*)w;  w += (size_t)BL*D_MODEL*2;
  unsigned short* Win_h  = (unsigned short*)w;  w += (size_t)NPAD1*D_MODEL*2;
  unsigned short* Wg_h   = (unsigned short*)w;  w += (size_t)D_MODEL*D_INNER*2;
  unsigned short* states = (unsigned short*)w;  w += (size_t)B_SZ*NCHUNK*NHEADS*HEADDIM*D_STATE*2;
  unsigned short* G      = (unsigned short*)w;  w += (size_t)B_SZ*NCHUNK*CHUNK*CHUNK*2;
  float* dt     = (float*)w;  w += (size_t)BL*NHEADS*4;
  float* A_cum  = (float*)w;  w += (size_t)B_SZ*NHEADS*NCHUNK*CHUNK*4;
  float* sc     = (float*)w;  w += (size_t)BL*4;

  // 0) all converts in one launch (Wg = W_out * norm_w, RMS fold)
  cvt_all<<<(NCVT+255)/256, 256, 0, stream>>>(u, W_in, W_out, norm_w, u_h, Win_h, Wg_h);
  // 1) zxbcdt = u @ W_in.T  (fp16 out; includes dt logit columns)
  gemm_f16_pipe<1><<<dim3(NPAD1/128, BL/128), 256, 0, stream>>>(u_h, Win_h, zx_h, nullptr, DPROJ, D_MODEL);
  // 2) dt + per-chunk cumsum (fused, shfl prefix)
  dtacum_kernel<<<B_SZ*NHEADS*NCHUNK, 64, 0, stream>>>(zx_h, dt_bias, A_log, dt, A_cum);
  // 3) depthwise conv + silu (fp16 in/out)
  conv8_kernel<<<((BL/8)*(CONV_DIM/4)+255)/256, 256, 0, stream>>>(zx_h, conv_w, conv_b, xBC_h);
  // 4) G = C B^T per (b,c), fp16 out
  g_kernel<<<B_SZ*NCHUNK*4, 256, 0, stream>>>(xBC_h, G);
  // 5) per-chunk states (MFMA, fp16 out)
  states_mfma<<<B_SZ*NCHUNK*NHEADS, 256, 0, stream>>>(xBC_h, dt, A_cum, states);
  // 6) inter-chunk scan (prefetch-all + serial recurrence), 8-way split
  scan_kernel<<<B_SZ*NHEADS*8, 256, 0, stream>>>(A_cum, states);
  // 7) Y (MFMA), fp16 out (unnormalized)
  y_mfma<<<B_SZ*NCHUNK*NHEADS, 256, 0, stream>>>(xBC_h, zx_h, dt, A_cum, G, states, Dp, ypre_h);
  // 8) per-row RMS scale
  rowsc_kernel<<<BL, 256, 0, stream>>>(ypre_h, sc);
  // 9) out = diag(sc) * (ypre @ (W_out*norm_w).T)  (64x128 tile, 3 blocks/CU)
  gemm_f16_64<<<dim3(D_MODEL/128, BL/64), 256, 0, stream>>>(ypre_h, Wg_h, out, sc, D_MODEL, D_INNER);
}